// Round 2
// baseline (31.296 us; speedup 1.0000x reference)
//
#include <hip/hip_runtime.h>

#define OUT 224
#define NIMG 64
#define NCH 3
#define IMH 1080
#define IMW 1920

__global__ __launch_bounds__(256) void roi_extract_kernel(
    const float* __restrict__ features,   // [N,C,H,W]
    const int*   __restrict__ detections, // [N,4] x1,y1,x2,y2
    float*       __restrict__ out)        // [N,C,OUT,OUT]
{
    const int idx = blockIdx.x * blockDim.x + threadIdx.x;
    const int total = NIMG * NCH * OUT * OUT;
    if (idx >= total) return;

    const int ox = idx % OUT;
    const int oy = (idx / OUT) % OUT;
    const int c  = (idx / (OUT * OUT)) % NCH;
    const int n  = idx / (OUT * OUT * NCH);

    // box (broadcast via cache: all threads of an image hit the same 16 B)
    const int x1 = detections[n * 4 + 0];
    const int y1 = detections[n * 4 + 1];
    const int x2 = detections[n * 4 + 2];
    const int y2 = detections[n * 4 + 3];

    const float bh = (float)(y2 - y1);
    const float bw = (float)(x2 - x1);

    // source coords, half-pixel centers, align_corners=False
    float ysf = ((float)oy + 0.5f) * bh * (1.0f / OUT) - 0.5f;
    float xsf = ((float)ox + 0.5f) * bw * (1.0f / OUT) - 0.5f;
    // clamp to crop interior (edge replication), shift into image coords
    ysf = fminf(fmaxf(ysf, 0.0f), bh - 1.0f) + (float)y1;
    xsf = fminf(fmaxf(xsf, 0.0f), bw - 1.0f) + (float)x1;

    const float y0f = floorf(ysf);
    const float x0f = floorf(xsf);
    const float wy = ysf - y0f;
    const float wx = xsf - x0f;

    int y0 = (int)y0f;  y0 = min(max(y0, 0), IMH - 1);
    int x0 = (int)x0f;  x0 = min(max(x0, 0), IMW - 1);
    const int y1i = min(y0 + 1, IMH - 1);
    const int x1i = min(x0 + 1, IMW - 1);

    const float* __restrict__ base =
        features + ((size_t)n * NCH + c) * (size_t)(IMH * IMW);

    const float v00 = base[(size_t)y0  * IMW + x0 ];
    const float v01 = base[(size_t)y0  * IMW + x1i];
    const float v10 = base[(size_t)y1i * IMW + x0 ];
    const float v11 = base[(size_t)y1i * IMW + x1i];

    const float top = v00 * (1.0f - wx) + v01 * wx;
    const float bot = v10 * (1.0f - wx) + v11 * wx;
    out[idx] = top * (1.0f - wy) + bot * wy;
}

extern "C" void kernel_launch(void* const* d_in, const int* in_sizes, int n_in,
                              void* d_out, int out_size, void* d_ws, size_t ws_size,
                              hipStream_t stream) {
    const float* features   = (const float*)d_in[0];
    const int*   detections = (const int*)d_in[1];
    float*       out        = (float*)d_out;

    const int total = NIMG * NCH * OUT * OUT;
    const int block = 256;
    const int grid  = (total + block - 1) / block;
    roi_extract_kernel<<<grid, block, 0, stream>>>(features, detections, out);
}

// Round 3
// 30.767 us; speedup vs baseline: 1.0172x; 1.0172x over previous
//
#include <hip/hip_runtime.h>

#define OUT 224
#define NIMG 64
#define NCH 3
#define IMH 1080
#define IMW 1920

// 4 output pixels per thread along x: OUT/4 = 56 thread-columns per row.
#define XV 4
#define OUTV (OUT / XV)

__global__ __launch_bounds__(256) void roi_extract_v4_kernel(
    const float* __restrict__ features,   // [N,C,H,W]
    const int4*  __restrict__ detections, // [N] {x1,y1,x2,y2}
    float4*      __restrict__ out)        // [N,C,OUT,OUT/4]
{
    const int idx = blockIdx.x * blockDim.x + threadIdx.x;
    const int total = NIMG * NCH * OUT * OUTV;
    if (idx >= total) return;

    const int oxv = idx % OUTV;             // vector column
    const int oy  = (idx / OUTV) % OUT;
    const int c   = (idx / (OUTV * OUT)) % NCH;
    const int n   = idx / (OUTV * OUT * NCH);

    const int4 box = detections[n];
    const float bh = (float)(box.w - box.y);
    const float bw = (float)(box.z - box.x);
    const float fy1 = (float)box.y;
    const float fx1 = (float)box.x;

    // ---- y setup (shared by the 4 outputs) ----
    float ysf = ((float)oy + 0.5f) * bh * (1.0f / OUT) - 0.5f;
    ysf = fminf(fmaxf(ysf, 0.0f), bh - 1.0f) + fy1;
    const float y0f = floorf(ysf);
    const float wy  = ysf - y0f;
    int y0 = min(max((int)y0f, 0), IMH - 1);
    const int y1i = min(y0 + 1, IMH - 1);

    const float* __restrict__ base =
        features + ((size_t)n * NCH + c) * (size_t)(IMH * IMW);
    const float* __restrict__ row0 = base + (size_t)y0  * IMW;
    const float* __restrict__ row1 = base + (size_t)y1i * IMW;

    const int ox0 = oxv * XV;

    float res[XV];
#pragma unroll
    for (int j = 0; j < XV; ++j) {
        float xsf = ((float)(ox0 + j) + 0.5f) * bw * (1.0f / OUT) - 0.5f;
        xsf = fminf(fmaxf(xsf, 0.0f), bw - 1.0f) + fx1;
        const float x0f = floorf(xsf);
        const float wx  = xsf - x0f;
        int x0 = min(max((int)x0f, 0), IMW - 1);
        const int x1i = min(x0 + 1, IMW - 1);

        const float v00 = row0[x0];
        const float v01 = row0[x1i];
        const float v10 = row1[x0];
        const float v11 = row1[x1i];

        const float top = v00 + (v01 - v00) * wx;
        const float bot = v10 + (v11 - v10) * wx;
        res[j] = top + (bot - top) * wy;
    }

    out[idx] = make_float4(res[0], res[1], res[2], res[3]);
}

extern "C" void kernel_launch(void* const* d_in, const int* in_sizes, int n_in,
                              void* d_out, int out_size, void* d_ws, size_t ws_size,
                              hipStream_t stream) {
    const float* features   = (const float*)d_in[0];
    const int4*  detections = (const int4*)d_in[1];
    float4*      out        = (float4*)d_out;

    const int total = NIMG * NCH * OUT * OUTV;
    const int block = 256;
    const int grid  = (total + block - 1) / block;
    roi_extract_v4_kernel<<<grid, block, 0, stream>>>(features, detections, out);
}